// Round 3
// baseline (755.133 us; speedup 1.0000x reference)
//
#include <hip/hip_runtime.h>

#define IN_CH   128
#define OUT_CH  64
#define M_TILE  128         // nodes per block in the MFMA GEMM
#define XS_PITCH 136        // 128 bf16 + 8 pad (272 B row) -> conflict-free frags
#define NBIN    256         // degree bins for counting sort

typedef __attribute__((ext_vector_type(8))) short short8;
typedef __attribute__((ext_vector_type(4))) float floatx4;

__device__ __forceinline__ unsigned short f2bf(float f) {
    union { float f; unsigned u; } v; v.f = f;
    unsigned r = v.u + 0x7fffu + ((v.u >> 16) & 1u);   // RNE
    return (unsigned short)(r >> 16);
}
__device__ __forceinline__ float bfl(unsigned u) {   // low bf16 -> f32
    return __uint_as_float(u << 16);
}
__device__ __forceinline__ float bfh(unsigned u) {   // high bf16 -> f32
    return __uint_as_float(u & 0xffff0000u);
}

// ---------------------------------------------------------------------------
// Kernel 1 (prep): CSR row pointers (lower_bound over sorted targets) for both
// edge sets, bf16 pre-pack of combined transposed weights, and zeroing of the
// degree histogram (tail threads).
// ---------------------------------------------------------------------------
__global__ void prep_kernel(const int* __restrict__ tgtIn,
                            const int* __restrict__ tgtOut,
                            const float* __restrict__ Wmi,
                            const float* __restrict__ Wmo,
                            const float* __restrict__ Wsh,
                            int* __restrict__ rpIn,
                            int* __restrict__ rpOut,
                            unsigned short* __restrict__ WcT,
                            int* __restrict__ hist,
                            int n_nodes, int neIn, int neOut)
{
    int i = blockIdx.x * blockDim.x + threadIdx.x;
    int half = n_nodes + 1;
    if (i < 2 * half) {
        const int* tgt; int* rp; int t; int ne;
        if (i < half) { tgt = tgtIn;  rp = rpIn;  t = i;        ne = neIn; }
        else          { tgt = tgtOut; rp = rpOut; t = i - half; ne = neOut; }
        int lo = 0, hi = ne;
        while (lo < hi) {
            int mid = (lo + hi) >> 1;
            if (tgt[mid] < t) lo = mid + 1; else hi = mid;
        }
        rp[t] = lo;
    } else {
        int j = i - 2 * half;
        if (j < 2 * OUT_CH * IN_CH) {
            int n = j >> 7, k = j & 127;     // n: output col of Wc, k: input ch
            float m = (n < OUT_CH) ? Wmi[k * OUT_CH + n]
                                   : Wmo[k * OUT_CH + (n - OUT_CH)];
            float s = Wsh[k * OUT_CH + (n & (OUT_CH - 1))];
            WcT[n * IN_CH + k] = f2bf(m + s);
        } else {
            int h = j - 2 * OUT_CH * IN_CH;
            if (h < NBIN) hist[h] = 0;
        }
    }
}

// ---------------------------------------------------------------------------
// Degree-binning counting sort (3 micro-kernels). Groups of 8 consecutive
// perm-slots then have near-equal combined degree, killing the max-of-8
// padding in prop (R1's measured +55% slot overhead).
// Order within a bin is arbitrary (atomic race) — results are unaffected:
// per-node edge processing order is unchanged.
// ---------------------------------------------------------------------------
__global__ void bin_hist_kernel(const int* __restrict__ rpIn,
                                const int* __restrict__ rpOut,
                                int* __restrict__ hist, int n_nodes)
{
    int t = blockIdx.x * blockDim.x + threadIdx.x;
    if (t < n_nodes) {
        int d = (rpIn[t + 1] - rpIn[t]) + (rpOut[t + 1] - rpOut[t]);
        atomicAdd(&hist[min(d, NBIN - 1)], 1);
    }
}

__global__ void bin_scan_kernel(const int* __restrict__ hist,
                                int* __restrict__ offs)   // 1 block, 256 thr
{
    __shared__ int s[NBIN];
    int tid = threadIdx.x;
    s[tid] = hist[tid];
    __syncthreads();
    // Hillis-Steele inclusive scan
    for (int d = 1; d < NBIN; d <<= 1) {
        int v = (tid >= d) ? s[tid - d] : 0;
        __syncthreads();
        s[tid] += v;
        __syncthreads();
    }
    offs[tid] = (tid == 0) ? 0 : s[tid - 1];   // exclusive
}

__global__ void bin_scatter_kernel(const int* __restrict__ rpIn,
                                   const int* __restrict__ rpOut,
                                   int* __restrict__ offs,
                                   int* __restrict__ perm, int n_nodes)
{
    int t = blockIdx.x * blockDim.x + threadIdx.x;
    if (t < n_nodes) {
        int d = (rpIn[t + 1] - rpIn[t]) + (rpOut[t + 1] - rpOut[t]);
        int pos = atomicAdd(&offs[min(d, NBIN - 1)], 1);
        perm[pos] = t;
    }
}

// ---------------------------------------------------------------------------
// Kernel 2 (MFMA GEMM): H = x_bf16 @ WcT^T. Unchanged (proven).
// ---------------------------------------------------------------------------
__global__ __launch_bounds__(256, 3)
void gemm_kernel(const float* __restrict__ x,
                 const unsigned short* __restrict__ WcT,
                 unsigned short* __restrict__ Abf,
                 unsigned short* __restrict__ Bbf,
                 int n_nodes)
{
    __shared__ unsigned short Xs[M_TILE][XS_PITCH];   // 34.8 KB

    const int tid  = threadIdx.x;
    const int w    = tid >> 6;
    const int lane = tid & 63;
    const int l15  = lane & 15;
    const int quad = lane >> 4;
    const long long node0 = (long long)blockIdx.x * M_TILE;

    short8 bfrag[4][2];
#pragma unroll
    for (int ks = 0; ks < 4; ++ks)
#pragma unroll
        for (int ni = 0; ni < 2; ++ni)
            bfrag[ks][ni] = *(const short8*)&WcT[(w * 32 + ni * 16 + l15) * IN_CH
                                                 + ks * 32 + quad * 8];

    {
        const float4* x4 = (const float4*)x;
        for (int i = tid; i < M_TILE * (IN_CH / 4); i += 256) {
            int row = i >> 5, c4 = i & 31;
            long long node = node0 + row;
            float4 v = make_float4(0.f, 0.f, 0.f, 0.f);
            if (node < n_nodes) v = x4[node * (IN_CH / 4) + c4];
            uint2 p;
            p.x = ((unsigned)f2bf(v.y) << 16) | f2bf(v.x);
            p.y = ((unsigned)f2bf(v.w) << 16) | f2bf(v.z);
            *(uint2*)&Xs[row][c4 * 4] = p;
        }
    }
    __syncthreads();

    floatx4 acc[8][2];
#pragma unroll
    for (int mi = 0; mi < 8; ++mi)
#pragma unroll
        for (int ni = 0; ni < 2; ++ni)
            acc[mi][ni] = (floatx4){0.f, 0.f, 0.f, 0.f};

#pragma unroll
    for (int ks = 0; ks < 4; ++ks) {
        const int k0 = ks * 32 + quad * 8;
#pragma unroll
        for (int mi = 0; mi < 8; ++mi) {
            short8 a = *(const short8*)&Xs[mi * 16 + l15][k0];
            acc[mi][0] = __builtin_amdgcn_mfma_f32_16x16x32_bf16(a, bfrag[ks][0], acc[mi][0], 0, 0, 0);
            acc[mi][1] = __builtin_amdgcn_mfma_f32_16x16x32_bf16(a, bfrag[ks][1], acc[mi][1], 0, 0, 0);
        }
    }

    unsigned short* Hout = (w < 2) ? Abf : Bbf;
    const int colb = (w & 1) * 32;
#pragma unroll
    for (int mi = 0; mi < 8; ++mi)
#pragma unroll
        for (int ni = 0; ni < 2; ++ni)
#pragma unroll
            for (int r = 0; r < 4; ++r) {
                long long row = node0 + mi * 16 + quad * 4 + r;
                if (row < n_nodes)
                    Hout[row * OUT_CH + colb + ni * 16 + l15] = f2bf(acc[mi][ni][r]);
            }
}

// ---------------------------------------------------------------------------
// Kernel 3: segmented weighted gather-sum + epilogue.
// R1's proven pipelined eighth-wave structure, verbatim, with ONE change:
// the node handled by slot t is perm[t] (degree-sorted), so the 8 nodes in a
// wave's eighth-group have near-equal combined degree and the max-of-8
// padding (~+55% slots at random order) collapses to ~+5%.
// ---------------------------------------------------------------------------
__global__ __launch_bounds__(256)
void prop_kernel(const unsigned short* __restrict__ H,   // A base; B = A + Boff
                 const int* __restrict__ rpIn, const int* __restrict__ rpOut,
                 const int* __restrict__ srcIn, const float* __restrict__ ewIn,
                 const int* __restrict__ srcOut, const float* __restrict__ ewOut,
                 const int* __restrict__ perm,
                 const float* __restrict__ bmi, const float* __restrict__ bmo,
                 const float* __restrict__ bsi, const float* __restrict__ bso,
                 const float* __restrict__ Cin, const float* __restrict__ Cout,
                 float* __restrict__ out, int n_nodes, int neIn, int neOut)
{
    const int lane = threadIdx.x & 63;
    const int wv   = threadIdx.x >> 6;
    const int e    = lane >> 3;           // eighth: which node of the eight
    const int el   = lane & 7;            // lane within eighth
    const int ch8  = el * 8;              // first of my 8 channels
    const int eb   = lane & 56;           // eighth base lane

    const unsigned short* Hq = H + ch8;   // per-lane channel-offset base

    const int t = ((int)blockIdx.x * 4 + wv) * 8 + e;
    const bool valid = (t < n_nodes);
    const int tc = valid ? perm[t] : 0;   // degree-sorted node id

    const int Boff = n_nodes * OUT_CH;    // element offset of B within H

    int ei0 = rpIn[tc],  ei1 = rpIn[tc + 1];
    int eo0 = rpOut[tc], eo1 = rpOut[tc + 1];
    int dIn  = ei1 - ei0;
    int len  = valid ? (dIn + (eo1 - eo0)) : 0;
    float ci = Cin[tc], co = Cout[tc];

    // Wave-uniform max combined length across the eight eighths (butterfly)
    int ml = len;
    ml = max(ml, __shfl_xor(ml, 8));
    ml = max(ml, __shfl_xor(ml, 16));
    ml = max(ml, __shfl_xor(ml, 32));
    const int maxlen = __builtin_amdgcn_readfirstlane(ml);

    float a0 = 0.f, a1 = 0.f, a2 = 0.f, a3 = 0.f;
    float a4 = 0.f, a5 = 0.f, a6 = 0.f, a7 = 0.f;

    // ---- raw pack loader: slot j of MY eighth's concatenated stream
    auto load_raw = [&](int j, int& sI, float& wI, int& sO, float& wO) {
        int iIn  = min(ei0 + max(0, min(j, dIn - 1)), neIn - 1);
        int jo   = j - dIn;
        int iOut = min(eo0 + max(0, jo), neOut - 1);
        sI = srcIn[iIn];  wI = ewIn[iIn];
        sO = srcOut[iOut]; wO = ewOut[iOut];
    };

    // ---- convert raw (sI,wI,sO,wO) at slot base p into (rowb, wj)
    auto conv = [&](int p, int sI, float wI, int sO, float wO,
                    int& rowb, float& wj) {
        int j = p + el;
        bool inSeg  = (j < dIn);
        bool anySeg = (j < len);
        int rb = inSeg ? (sI * OUT_CH) : (sO * OUT_CH + Boff);
        rowb = anySeg ? rb : 0;
        wj   = inSeg ? (ci * wI) : (anySeg ? (co * wO) : 0.f);
    };

    // ---- issue the 8 uint4 gathers of one pack (rows broadcast within eighth)
    auto gather = [&](int rowb, uint4 (&u)[8]) {
        int r0 = __shfl(rowb, eb + 0), r1 = __shfl(rowb, eb + 1);
        int r2 = __shfl(rowb, eb + 2), r3 = __shfl(rowb, eb + 3);
        int r4 = __shfl(rowb, eb + 4), r5 = __shfl(rowb, eb + 5);
        int r6 = __shfl(rowb, eb + 6), r7 = __shfl(rowb, eb + 7);
        u[0] = *(const uint4*)(Hq + r0);
        u[1] = *(const uint4*)(Hq + r1);
        u[2] = *(const uint4*)(Hq + r2);
        u[3] = *(const uint4*)(Hq + r3);
        u[4] = *(const uint4*)(Hq + r4);
        u[5] = *(const uint4*)(Hq + r5);
        u[6] = *(const uint4*)(Hq + r6);
        u[7] = *(const uint4*)(Hq + r7);
    };

    // ---- consume one pack: broadcast weights at use time, 128 FMAs
    auto consume = [&](const uint4 (&u)[8], float wj) {
#pragma unroll
        for (int k = 0; k < 8; ++k) {
            float wk = __shfl(wj, eb + k);
            uint4 uk = u[k];
            a0 += wk * bfl(uk.x); a1 += wk * bfh(uk.x);
            a2 += wk * bfl(uk.y); a3 += wk * bfh(uk.y);
            a4 += wk * bfl(uk.z); a5 += wk * bfh(uk.z);
            a6 += wk * bfl(uk.w); a7 += wk * bfh(uk.w);
        }
    };

    int   sIa, sOa, sIb, sOb;
    float wIa, wOa, wIb, wOb;
    uint4 uA[8], uB[8];
    float wjA = 0.f, wjB = 0.f;

    // ---- prologue: fill both pipeline stages
    load_raw(el,     sIa, wIa, sOa, wOa);    // pack offset 0 raws
    load_raw(8 + el, sIb, wIb, sOb, wOb);    // pack offset 8 raws
    {
        int rb; conv(0, sIa, wIa, sOa, wOa, rb, wjA);
        gather(rb, uA);                       // pack 0 gathers in flight
    }
    load_raw(16 + el, sIa, wIa, sOa, wOa);   // pack 16 raws (in flight)
    {
        int rb; conv(8, sIb, wIb, sOb, wOb, rb, wjB);
        gather(rb, uB);                       // pack 8 gathers in flight
    }
    load_raw(24 + el, sIb, wIb, sOb, wOb);   // pack 24 raws (in flight)

    // ---- steady state: consume pack p / p+8, prep pack p+16 / p+24
    for (int p = 0; p < maxlen; p += 16) {
        consume(uA, wjA);                     // pack p
        if (p + 16 < maxlen) {
            int rb; conv(p + 16, sIa, wIa, sOa, wOa, rb, wjA);
            load_raw(p + 32 + el, sIa, wIa, sOa, wOa);
            gather(rb, uA);                   // pack p+16 in flight
        }
        if (p + 8 < maxlen) consume(uB, wjB); // pack p+8
        if (p + 24 < maxlen) {
            int rb; conv(p + 24, sIb, wIb, sOb, wOb, rb, wjB);
            load_raw(p + 40 + el, sIb, wIb, sOb, wOb);
            gather(rb, uB);                   // pack p+24 in flight
        }
    }

    if (valid) {
        float4 o0, o1;
        o0.x = a0 + ci * (bmi[ch8 + 0] + bsi[ch8 + 0]) + co * (bmo[ch8 + 0] + bso[ch8 + 0]);
        o0.y = a1 + ci * (bmi[ch8 + 1] + bsi[ch8 + 1]) + co * (bmo[ch8 + 1] + bso[ch8 + 1]);
        o0.z = a2 + ci * (bmi[ch8 + 2] + bsi[ch8 + 2]) + co * (bmo[ch8 + 2] + bso[ch8 + 2]);
        o0.w = a3 + ci * (bmi[ch8 + 3] + bsi[ch8 + 3]) + co * (bmo[ch8 + 3] + bso[ch8 + 3]);
        o1.x = a4 + ci * (bmi[ch8 + 4] + bsi[ch8 + 4]) + co * (bmo[ch8 + 4] + bso[ch8 + 4]);
        o1.y = a5 + ci * (bmi[ch8 + 5] + bsi[ch8 + 5]) + co * (bmo[ch8 + 5] + bso[ch8 + 5]);
        o1.z = a6 + ci * (bmi[ch8 + 6] + bsi[ch8 + 6]) + co * (bmo[ch8 + 6] + bso[ch8 + 6]);
        o1.w = a7 + ci * (bmi[ch8 + 7] + bsi[ch8 + 7]) + co * (bmo[ch8 + 7] + bso[ch8 + 7]);
        float* ob = out + (long long)tc * OUT_CH + ch8;
        *(float4*)ob = o0;
        *(float4*)(ob + 4) = o1;
    }
}

// ---------------------------------------------------------------------------
extern "C" void kernel_launch(void* const* d_in, const int* in_sizes, int n_in,
                              void* d_out, int out_size, void* d_ws, size_t ws_size,
                              hipStream_t stream)
{
    const float* x    = (const float*)d_in[0];
    const float* Wmi  = (const float*)d_in[1];
    const float* Wmo  = (const float*)d_in[2];
    const float* Wsh  = (const float*)d_in[3];
    const float* bmi  = (const float*)d_in[4];
    const float* bmo  = (const float*)d_in[5];
    const float* bsi  = (const float*)d_in[6];
    const float* bso  = (const float*)d_in[7];
    const float* Cin  = (const float*)d_in[8];
    const float* Cout = (const float*)d_in[9];
    const int*   eiIn  = (const int*)d_in[10];
    const float* ewIn  = (const float*)d_in[11];
    const int*   eiOut = (const int*)d_in[12];
    const float* ewOut = (const float*)d_in[13];

    const int n_nodes = in_sizes[0] / IN_CH;   // 100000
    const int neIn  = in_sizes[11];            // 1000000
    const int neOut = in_sizes[13];

    const int* srcIn  = eiIn;                  // edge_index[0]
    const int* tgtIn  = eiIn + neIn;           // edge_index[1] (sorted)
    const int* srcOut = eiOut;
    const int* tgtOut = eiOut + neOut;

    // Workspace: Abf|Bbf (bf16) | rpIn | rpOut | WcT (bf16) | hist | offs | perm
    char* ws = (char*)d_ws;
    size_t NH = (size_t)n_nodes * OUT_CH * sizeof(unsigned short);
    unsigned short* Abf = (unsigned short*)ws;
    unsigned short* Bbf = (unsigned short*)(ws + NH);
    int* rpIn  = (int*)(ws + 2 * NH);
    int* rpOut = rpIn + (n_nodes + 1);
    unsigned short* WcT = (unsigned short*)(rpOut + (n_nodes + 1));
    int* hist = (int*)(WcT + 2 * OUT_CH * IN_CH);
    int* offs = hist + NBIN;
    int* perm = offs + NBIN;

    // 1) rowptrs + combined-weight bf16 pre-pack + hist zero
    int prep_threads = 2 * (n_nodes + 1) + 2 * OUT_CH * IN_CH + NBIN;
    prep_kernel<<<(prep_threads + 255) / 256, 256, 0, stream>>>(
        tgtIn, tgtOut, Wmi, Wmo, Wsh, rpIn, rpOut, WcT, hist, n_nodes, neIn, neOut);

    // 1b) degree counting sort -> perm
    int nblk = (n_nodes + 255) / 256;
    bin_hist_kernel<<<nblk, 256, 0, stream>>>(rpIn, rpOut, hist, n_nodes);
    bin_scan_kernel<<<1, NBIN, 0, stream>>>(hist, offs);
    bin_scatter_kernel<<<nblk, 256, 0, stream>>>(rpIn, rpOut, offs, perm, n_nodes);

    // 2) fused dense transform via MFMA (N=128 GEMM: [A|B] columns)
    int gblocks = (n_nodes + M_TILE - 1) / M_TILE;
    gemm_kernel<<<gblocks, 256, 0, stream>>>(x, WcT, Abf, Bbf, n_nodes);

    // 3) segmented gather-sum + epilogue (pipelined, degree-sorted groups)
    int pblocks = (n_nodes + 31) / 32;         // 32 nodes per block
    prop_kernel<<<pblocks, 256, 0, stream>>>(
        Abf, rpIn, rpOut, srcIn, ewIn, srcOut, ewOut, perm,
        bmi, bmo, bsi, bso, Cin, Cout, (float*)d_out, n_nodes, neIn, neOut);
}

// Round 4
// 213.259 us; speedup vs baseline: 3.5409x; 3.5409x over previous
//
#include <hip/hip_runtime.h>

#define IN_CH   128
#define OUT_CH  64
#define M_TILE  128         // nodes per block in the MFMA GEMM
#define XS_PITCH 136        // 128 bf16 + 8 pad (272 B row) -> conflict-free frags
#define NBIN    256         // degree bins for counting sort

typedef __attribute__((ext_vector_type(8))) short short8;
typedef __attribute__((ext_vector_type(4))) float floatx4;

__device__ __forceinline__ unsigned short f2bf(float f) {
    union { float f; unsigned u; } v; v.f = f;
    unsigned r = v.u + 0x7fffu + ((v.u >> 16) & 1u);   // RNE
    return (unsigned short)(r >> 16);
}
__device__ __forceinline__ float bfl(unsigned u) {   // low bf16 -> f32
    return __uint_as_float(u << 16);
}
__device__ __forceinline__ float bfh(unsigned u) {   // high bf16 -> f32
    return __uint_as_float(u & 0xffff0000u);
}

// ---------------------------------------------------------------------------
// Kernel 1 (prep): CSR row pointers (lower_bound over sorted targets) for both
// edge sets, bf16 pre-pack of combined transposed weights, and zeroing of the
// degree histogram (tail threads).
// ---------------------------------------------------------------------------
__global__ void prep_kernel(const int* __restrict__ tgtIn,
                            const int* __restrict__ tgtOut,
                            const float* __restrict__ Wmi,
                            const float* __restrict__ Wmo,
                            const float* __restrict__ Wsh,
                            int* __restrict__ rpIn,
                            int* __restrict__ rpOut,
                            unsigned short* __restrict__ WcT,
                            int* __restrict__ hist,
                            int n_nodes, int neIn, int neOut)
{
    int i = blockIdx.x * blockDim.x + threadIdx.x;
    int half = n_nodes + 1;
    if (i < 2 * half) {
        const int* tgt; int* rp; int t; int ne;
        if (i < half) { tgt = tgtIn;  rp = rpIn;  t = i;        ne = neIn; }
        else          { tgt = tgtOut; rp = rpOut; t = i - half; ne = neOut; }
        int lo = 0, hi = ne;
        while (lo < hi) {
            int mid = (lo + hi) >> 1;
            if (tgt[mid] < t) lo = mid + 1; else hi = mid;
        }
        rp[t] = lo;
    } else {
        int j = i - 2 * half;
        if (j < 2 * OUT_CH * IN_CH) {
            int n = j >> 7, k = j & 127;     // n: output col of Wc, k: input ch
            float m = (n < OUT_CH) ? Wmi[k * OUT_CH + n]
                                   : Wmo[k * OUT_CH + (n - OUT_CH)];
            float s = Wsh[k * OUT_CH + (n & (OUT_CH - 1))];
            WcT[n * IN_CH + k] = f2bf(m + s);
        } else {
            int h = j - 2 * OUT_CH * IN_CH;
            if (h < NBIN) hist[h] = 0;
        }
    }
}

// ---------------------------------------------------------------------------
// Degree-binning counting sort. R3 lesson: naive per-node global atomics on
// 256 bins serialize (~5-9K same-address atomics on hot bins = 277 us).
// Two-level version: LDS histogram per block, ONE global atomic per
// (block, nonempty bin). Scatter reserves a contiguous chunk per (block,bin)
// and places nodes conflict-free. Order within a bin is block-arbitrary --
// irrelevant (per-node edge order unchanged).
// ---------------------------------------------------------------------------
__global__ __launch_bounds__(256)
void bin_hist_kernel(const int* __restrict__ rpIn,
                     const int* __restrict__ rpOut,
                     int* __restrict__ hist, int n_nodes)
{
    __shared__ int lh[NBIN];
    const int tid = threadIdx.x;
    lh[tid] = 0;
    __syncthreads();
    int t = blockIdx.x * 256 + tid;
    if (t < n_nodes) {
        int d = (rpIn[t + 1] - rpIn[t]) + (rpOut[t + 1] - rpOut[t]);
        atomicAdd(&lh[min(d, NBIN - 1)], 1);          // LDS atomic
    }
    __syncthreads();
    int c = lh[tid];
    if (c > 0) atomicAdd(&hist[tid], c);              // one global add per bin
}

__global__ void bin_scan_kernel(const int* __restrict__ hist,
                                int* __restrict__ offs)   // 1 block, 256 thr
{
    __shared__ int s[NBIN];
    int tid = threadIdx.x;
    s[tid] = hist[tid];
    __syncthreads();
    // Hillis-Steele inclusive scan
    for (int d = 1; d < NBIN; d <<= 1) {
        int v = (tid >= d) ? s[tid - d] : 0;
        __syncthreads();
        s[tid] += v;
        __syncthreads();
    }
    offs[tid] = (tid == 0) ? 0 : s[tid - 1];   // exclusive
}

__global__ __launch_bounds__(256)
void bin_scatter_kernel(const int* __restrict__ rpIn,
                        const int* __restrict__ rpOut,
                        int* __restrict__ offs,
                        int* __restrict__ perm, int n_nodes)
{
    __shared__ int lh[NBIN];      // local per-bin count
    __shared__ int lbase[NBIN];   // reserved global base for this block
    const int tid = threadIdx.x;
    lh[tid] = 0;
    __syncthreads();
    int t = blockIdx.x * 256 + tid;
    int bin = 0, local = 0;
    if (t < n_nodes) {
        int d = (rpIn[t + 1] - rpIn[t]) + (rpOut[t + 1] - rpOut[t]);
        bin = min(d, NBIN - 1);
        local = atomicAdd(&lh[bin], 1);               // LDS atomic: my rank
    }
    __syncthreads();
    int c = lh[tid];
    if (c > 0) lbase[tid] = atomicAdd(&offs[tid], c); // one global add per bin
    __syncthreads();
    if (t < n_nodes) perm[lbase[bin] + local] = t;    // conflict-free place
}

// ---------------------------------------------------------------------------
// Kernel 2 (MFMA GEMM): H = x_bf16 @ WcT^T. Unchanged (proven).
// ---------------------------------------------------------------------------
__global__ __launch_bounds__(256, 3)
void gemm_kernel(const float* __restrict__ x,
                 const unsigned short* __restrict__ WcT,
                 unsigned short* __restrict__ Abf,
                 unsigned short* __restrict__ Bbf,
                 int n_nodes)
{
    __shared__ unsigned short Xs[M_TILE][XS_PITCH];   // 34.8 KB

    const int tid  = threadIdx.x;
    const int w    = tid >> 6;
    const int lane = tid & 63;
    const int l15  = lane & 15;
    const int quad = lane >> 4;
    const long long node0 = (long long)blockIdx.x * M_TILE;

    short8 bfrag[4][2];
#pragma unroll
    for (int ks = 0; ks < 4; ++ks)
#pragma unroll
        for (int ni = 0; ni < 2; ++ni)
            bfrag[ks][ni] = *(const short8*)&WcT[(w * 32 + ni * 16 + l15) * IN_CH
                                                 + ks * 32 + quad * 8];

    {
        const float4* x4 = (const float4*)x;
        for (int i = tid; i < M_TILE * (IN_CH / 4); i += 256) {
            int row = i >> 5, c4 = i & 31;
            long long node = node0 + row;
            float4 v = make_float4(0.f, 0.f, 0.f, 0.f);
            if (node < n_nodes) v = x4[node * (IN_CH / 4) + c4];
            uint2 p;
            p.x = ((unsigned)f2bf(v.y) << 16) | f2bf(v.x);
            p.y = ((unsigned)f2bf(v.w) << 16) | f2bf(v.z);
            *(uint2*)&Xs[row][c4 * 4] = p;
        }
    }
    __syncthreads();

    floatx4 acc[8][2];
#pragma unroll
    for (int mi = 0; mi < 8; ++mi)
#pragma unroll
        for (int ni = 0; ni < 2; ++ni)
            acc[mi][ni] = (floatx4){0.f, 0.f, 0.f, 0.f};

#pragma unroll
    for (int ks = 0; ks < 4; ++ks) {
        const int k0 = ks * 32 + quad * 8;
#pragma unroll
        for (int mi = 0; mi < 8; ++mi) {
            short8 a = *(const short8*)&Xs[mi * 16 + l15][k0];
            acc[mi][0] = __builtin_amdgcn_mfma_f32_16x16x32_bf16(a, bfrag[ks][0], acc[mi][0], 0, 0, 0);
            acc[mi][1] = __builtin_amdgcn_mfma_f32_16x16x32_bf16(a, bfrag[ks][1], acc[mi][1], 0, 0, 0);
        }
    }

    unsigned short* Hout = (w < 2) ? Abf : Bbf;
    const int colb = (w & 1) * 32;
#pragma unroll
    for (int mi = 0; mi < 8; ++mi)
#pragma unroll
        for (int ni = 0; ni < 2; ++ni)
#pragma unroll
            for (int r = 0; r < 4; ++r) {
                long long row = node0 + mi * 16 + quad * 4 + r;
                if (row < n_nodes)
                    Hout[row * OUT_CH + colb + ni * 16 + l15] = f2bf(acc[mi][ni][r]);
            }
}

// ---------------------------------------------------------------------------
// Kernel 3: segmented weighted gather-sum + epilogue.
// R1's proven pipelined eighth-wave structure with perm[] (degree-sorted
// groups of 8 -> max-of-8 padding ~+55% -> ~+5%). Unchanged from R3.
// ---------------------------------------------------------------------------
__global__ __launch_bounds__(256)
void prop_kernel(const unsigned short* __restrict__ H,   // A base; B = A + Boff
                 const int* __restrict__ rpIn, const int* __restrict__ rpOut,
                 const int* __restrict__ srcIn, const float* __restrict__ ewIn,
                 const int* __restrict__ srcOut, const float* __restrict__ ewOut,
                 const int* __restrict__ perm,
                 const float* __restrict__ bmi, const float* __restrict__ bmo,
                 const float* __restrict__ bsi, const float* __restrict__ bso,
                 const float* __restrict__ Cin, const float* __restrict__ Cout,
                 float* __restrict__ out, int n_nodes, int neIn, int neOut)
{
    const int lane = threadIdx.x & 63;
    const int wv   = threadIdx.x >> 6;
    const int e    = lane >> 3;           // eighth: which node of the eight
    const int el   = lane & 7;            // lane within eighth
    const int ch8  = el * 8;              // first of my 8 channels
    const int eb   = lane & 56;           // eighth base lane

    const unsigned short* Hq = H + ch8;   // per-lane channel-offset base

    const int t = ((int)blockIdx.x * 4 + wv) * 8 + e;
    const bool valid = (t < n_nodes);
    const int tc = valid ? perm[t] : 0;   // degree-sorted node id

    const int Boff = n_nodes * OUT_CH;    // element offset of B within H

    int ei0 = rpIn[tc],  ei1 = rpIn[tc + 1];
    int eo0 = rpOut[tc], eo1 = rpOut[tc + 1];
    int dIn  = ei1 - ei0;
    int len  = valid ? (dIn + (eo1 - eo0)) : 0;
    float ci = Cin[tc], co = Cout[tc];

    // Wave-uniform max combined length across the eight eighths (butterfly)
    int ml = len;
    ml = max(ml, __shfl_xor(ml, 8));
    ml = max(ml, __shfl_xor(ml, 16));
    ml = max(ml, __shfl_xor(ml, 32));
    const int maxlen = __builtin_amdgcn_readfirstlane(ml);

    float a0 = 0.f, a1 = 0.f, a2 = 0.f, a3 = 0.f;
    float a4 = 0.f, a5 = 0.f, a6 = 0.f, a7 = 0.f;

    // ---- raw pack loader: slot j of MY eighth's concatenated stream
    auto load_raw = [&](int j, int& sI, float& wI, int& sO, float& wO) {
        int iIn  = min(ei0 + max(0, min(j, dIn - 1)), neIn - 1);
        int jo   = j - dIn;
        int iOut = min(eo0 + max(0, jo), neOut - 1);
        sI = srcIn[iIn];  wI = ewIn[iIn];
        sO = srcOut[iOut]; wO = ewOut[iOut];
    };

    // ---- convert raw (sI,wI,sO,wO) at slot base p into (rowb, wj)
    auto conv = [&](int p, int sI, float wI, int sO, float wO,
                    int& rowb, float& wj) {
        int j = p + el;
        bool inSeg  = (j < dIn);
        bool anySeg = (j < len);
        int rb = inSeg ? (sI * OUT_CH) : (sO * OUT_CH + Boff);
        rowb = anySeg ? rb : 0;
        wj   = inSeg ? (ci * wI) : (anySeg ? (co * wO) : 0.f);
    };

    // ---- issue the 8 uint4 gathers of one pack (rows broadcast within eighth)
    auto gather = [&](int rowb, uint4 (&u)[8]) {
        int r0 = __shfl(rowb, eb + 0), r1 = __shfl(rowb, eb + 1);
        int r2 = __shfl(rowb, eb + 2), r3 = __shfl(rowb, eb + 3);
        int r4 = __shfl(rowb, eb + 4), r5 = __shfl(rowb, eb + 5);
        int r6 = __shfl(rowb, eb + 6), r7 = __shfl(rowb, eb + 7);
        u[0] = *(const uint4*)(Hq + r0);
        u[1] = *(const uint4*)(Hq + r1);
        u[2] = *(const uint4*)(Hq + r2);
        u[3] = *(const uint4*)(Hq + r3);
        u[4] = *(const uint4*)(Hq + r4);
        u[5] = *(const uint4*)(Hq + r5);
        u[6] = *(const uint4*)(Hq + r6);
        u[7] = *(const uint4*)(Hq + r7);
    };

    // ---- consume one pack: broadcast weights at use time, 128 FMAs
    auto consume = [&](const uint4 (&u)[8], float wj) {
#pragma unroll
        for (int k = 0; k < 8; ++k) {
            float wk = __shfl(wj, eb + k);
            uint4 uk = u[k];
            a0 += wk * bfl(uk.x); a1 += wk * bfh(uk.x);
            a2 += wk * bfl(uk.y); a3 += wk * bfh(uk.y);
            a4 += wk * bfl(uk.z); a5 += wk * bfh(uk.z);
            a6 += wk * bfl(uk.w); a7 += wk * bfh(uk.w);
        }
    };

    int   sIa, sOa, sIb, sOb;
    float wIa, wOa, wIb, wOb;
    uint4 uA[8], uB[8];
    float wjA = 0.f, wjB = 0.f;

    // ---- prologue: fill both pipeline stages
    load_raw(el,     sIa, wIa, sOa, wOa);    // pack offset 0 raws
    load_raw(8 + el, sIb, wIb, sOb, wOb);    // pack offset 8 raws
    {
        int rb; conv(0, sIa, wIa, sOa, wOa, rb, wjA);
        gather(rb, uA);                       // pack 0 gathers in flight
    }
    load_raw(16 + el, sIa, wIa, sOa, wOa);   // pack 16 raws (in flight)
    {
        int rb; conv(8, sIb, wIb, sOb, wOb, rb, wjB);
        gather(rb, uB);                       // pack 8 gathers in flight
    }
    load_raw(24 + el, sIb, wIb, sOb, wOb);   // pack 24 raws (in flight)

    // ---- steady state: consume pack p / p+8, prep pack p+16 / p+24
    for (int p = 0; p < maxlen; p += 16) {
        consume(uA, wjA);                     // pack p
        if (p + 16 < maxlen) {
            int rb; conv(p + 16, sIa, wIa, sOa, wOa, rb, wjA);
            load_raw(p + 32 + el, sIa, wIa, sOa, wOa);
            gather(rb, uA);                   // pack p+16 in flight
        }
        if (p + 8 < maxlen) consume(uB, wjB); // pack p+8
        if (p + 24 < maxlen) {
            int rb; conv(p + 24, sIb, wIb, sOb, wOb, rb, wjB);
            load_raw(p + 40 + el, sIb, wIb, sOb, wOb);
            gather(rb, uB);                   // pack p+24 in flight
        }
    }

    if (valid) {
        float4 o0, o1;
        o0.x = a0 + ci * (bmi[ch8 + 0] + bsi[ch8 + 0]) + co * (bmo[ch8 + 0] + bso[ch8 + 0]);
        o0.y = a1 + ci * (bmi[ch8 + 1] + bsi[ch8 + 1]) + co * (bmo[ch8 + 1] + bso[ch8 + 1]);
        o0.z = a2 + ci * (bmi[ch8 + 2] + bsi[ch8 + 2]) + co * (bmo[ch8 + 2] + bso[ch8 + 2]);
        o0.w = a3 + ci * (bmi[ch8 + 3] + bsi[ch8 + 3]) + co * (bmo[ch8 + 3] + bso[ch8 + 3]);
        o1.x = a4 + ci * (bmi[ch8 + 4] + bsi[ch8 + 4]) + co * (bmo[ch8 + 4] + bso[ch8 + 4]);
        o1.y = a5 + ci * (bmi[ch8 + 5] + bsi[ch8 + 5]) + co * (bmo[ch8 + 5] + bso[ch8 + 5]);
        o1.z = a6 + ci * (bmi[ch8 + 6] + bsi[ch8 + 6]) + co * (bmo[ch8 + 6] + bso[ch8 + 6]);
        o1.w = a7 + ci * (bmi[ch8 + 7] + bsi[ch8 + 7]) + co * (bmo[ch8 + 7] + bso[ch8 + 7]);
        float* ob = out + (long long)tc * OUT_CH + ch8;
        *(float4*)ob = o0;
        *(float4*)(ob + 4) = o1;
    }
}

// ---------------------------------------------------------------------------
extern "C" void kernel_launch(void* const* d_in, const int* in_sizes, int n_in,
                              void* d_out, int out_size, void* d_ws, size_t ws_size,
                              hipStream_t stream)
{
    const float* x    = (const float*)d_in[0];
    const float* Wmi  = (const float*)d_in[1];
    const float* Wmo  = (const float*)d_in[2];
    const float* Wsh  = (const float*)d_in[3];
    const float* bmi  = (const float*)d_in[4];
    const float* bmo  = (const float*)d_in[5];
    const float* bsi  = (const float*)d_in[6];
    const float* bso  = (const float*)d_in[7];
    const float* Cin  = (const float*)d_in[8];
    const float* Cout = (const float*)d_in[9];
    const int*   eiIn  = (const int*)d_in[10];
    const float* ewIn  = (const float*)d_in[11];
    const int*   eiOut = (const int*)d_in[12];
    const float* ewOut = (const float*)d_in[13];

    const int n_nodes = in_sizes[0] / IN_CH;   // 100000
    const int neIn  = in_sizes[11];            // 1000000
    const int neOut = in_sizes[13];

    const int* srcIn  = eiIn;                  // edge_index[0]
    const int* tgtIn  = eiIn + neIn;           // edge_index[1] (sorted)
    const int* srcOut = eiOut;
    const int* tgtOut = eiOut + neOut;

    // Workspace: Abf|Bbf (bf16) | rpIn | rpOut | WcT (bf16) | hist | offs | perm
    char* ws = (char*)d_ws;
    size_t NH = (size_t)n_nodes * OUT_CH * sizeof(unsigned short);
    unsigned short* Abf = (unsigned short*)ws;
    unsigned short* Bbf = (unsigned short*)(ws + NH);
    int* rpIn  = (int*)(ws + 2 * NH);
    int* rpOut = rpIn + (n_nodes + 1);
    unsigned short* WcT = (unsigned short*)(rpOut + (n_nodes + 1));
    int* hist = (int*)(WcT + 2 * OUT_CH * IN_CH);
    int* offs = hist + NBIN;
    int* perm = offs + NBIN;

    // 1) rowptrs + combined-weight bf16 pre-pack + hist zero
    int prep_threads = 2 * (n_nodes + 1) + 2 * OUT_CH * IN_CH + NBIN;
    prep_kernel<<<(prep_threads + 255) / 256, 256, 0, stream>>>(
        tgtIn, tgtOut, Wmi, Wmo, Wsh, rpIn, rpOut, WcT, hist, n_nodes, neIn, neOut);

    // 1b) degree counting sort -> perm (two-level, LDS-aggregated atomics)
    int nblk = (n_nodes + 255) / 256;
    bin_hist_kernel<<<nblk, 256, 0, stream>>>(rpIn, rpOut, hist, n_nodes);
    bin_scan_kernel<<<1, NBIN, 0, stream>>>(hist, offs);
    bin_scatter_kernel<<<nblk, 256, 0, stream>>>(rpIn, rpOut, offs, perm, n_nodes);

    // 2) fused dense transform via MFMA (N=128 GEMM: [A|B] columns)
    int gblocks = (n_nodes + M_TILE - 1) / M_TILE;
    gemm_kernel<<<gblocks, 256, 0, stream>>>(x, WcT, Abf, Bbf, n_nodes);

    // 3) segmented gather-sum + epilogue (pipelined, degree-sorted groups)
    int pblocks = (n_nodes + 31) / 32;         // 32 nodes per block
    prop_kernel<<<pblocks, 256, 0, stream>>>(
        Abf, rpIn, rpOut, srcIn, ewIn, srcOut, ewOut, perm,
        bmi, bmo, bsi, bso, Cin, Cout, (float*)d_out, n_nodes, neIn, neOut);
}

// Round 5
// 205.639 us; speedup vs baseline: 3.6721x; 1.0371x over previous
//
#include <hip/hip_runtime.h>

#define IN_CH   128
#define OUT_CH  64
#define M_TILE  128         // nodes per block in the MFMA GEMM
#define XS_PITCH 136        // 128 bf16 + 8 pad (272 B row) -> conflict-free frags

typedef __attribute__((ext_vector_type(8))) short short8;
typedef __attribute__((ext_vector_type(4))) float floatx4;

__device__ __forceinline__ unsigned short f2bf(float f) {
    union { float f; unsigned u; } v; v.f = f;
    unsigned r = v.u + 0x7fffu + ((v.u >> 16) & 1u);   // RNE
    return (unsigned short)(r >> 16);
}
__device__ __forceinline__ float bfl(unsigned u) {   // low bf16 -> f32
    return __uint_as_float(u << 16);
}
__device__ __forceinline__ float bfh(unsigned u) {   // high bf16 -> f32
    return __uint_as_float(u & 0xffff0000u);
}

// ---------------------------------------------------------------------------
// Kernel 1 (prep): CSR row pointers (lower_bound over sorted targets) for both
// edge sets + bf16 pre-pack of the combined transposed weights
// WcT[n][k] = bf16(Wc[k][n]), Wc = [Wmi+Ws | Wmo+Ws]  (128x128).
// ---------------------------------------------------------------------------
__global__ void prep_kernel(const int* __restrict__ tgtIn,
                            const int* __restrict__ tgtOut,
                            const float* __restrict__ Wmi,
                            const float* __restrict__ Wmo,
                            const float* __restrict__ Wsh,
                            int* __restrict__ rpIn,
                            int* __restrict__ rpOut,
                            unsigned short* __restrict__ WcT,
                            int n_nodes, int neIn, int neOut)
{
    int i = blockIdx.x * blockDim.x + threadIdx.x;
    int half = n_nodes + 1;
    if (i < 2 * half) {
        const int* tgt; int* rp; int t; int ne;
        if (i < half) { tgt = tgtIn;  rp = rpIn;  t = i;        ne = neIn; }
        else          { tgt = tgtOut; rp = rpOut; t = i - half; ne = neOut; }
        int lo = 0, hi = ne;
        while (lo < hi) {
            int mid = (lo + hi) >> 1;
            if (tgt[mid] < t) lo = mid + 1; else hi = mid;
        }
        rp[t] = lo;
    } else {
        int j = i - 2 * half;
        if (j < 2 * OUT_CH * IN_CH) {
            int n = j >> 7, k = j & 127;     // n: output col of Wc, k: input ch
            float m = (n < OUT_CH) ? Wmi[k * OUT_CH + n]
                                   : Wmo[k * OUT_CH + (n - OUT_CH)];
            float s = Wsh[k * OUT_CH + (n & (OUT_CH - 1))];
            WcT[n * IN_CH + k] = f2bf(m + s);
        }
    }
}

// ---------------------------------------------------------------------------
// Kernel 1b (wsort): degree sort WITHIN each 256-node window (LDS bitonic).
// R4 lesson: a GLOBAL degree sort equalizes group-of-8 degrees but scatters
// the groups' CSR edge ranges across the graph (FETCH 120->160 MB, prop
// +14 us). Window-local sort keeps each group's 8 nodes inside one 256-node
// neighborhood (edge ranges within ~20 KB -> R1-level locality) while
// adjacent order statistics of 256 iid degrees still make groups of 8
// near-uniform (padding ~+5% instead of +55%). No global atomics (R3 lesson).
// ---------------------------------------------------------------------------
__global__ __launch_bounds__(256)
void wsort_kernel(const int* __restrict__ rpIn, const int* __restrict__ rpOut,
                  int* __restrict__ perm, int n_nodes)
{
    __shared__ unsigned key[256];          // (deg<<16) | local_idx
    const int tid  = threadIdx.x;
    const int base = (int)blockIdx.x * 256;
    const int t    = base + tid;

    int d = 0x7FFF;                        // pads sort to the end
    if (t < n_nodes)
        d = min((rpIn[t + 1] - rpIn[t]) + (rpOut[t + 1] - rpOut[t]), 0x7FFE);
    key[tid] = ((unsigned)d << 16) | (unsigned)tid;

    // bitonic sort, 256 elements
    for (int k = 2; k <= 256; k <<= 1) {
        for (int j = k >> 1; j > 0; j >>= 1) {
            __syncthreads();
            int ixj = tid ^ j;
            if (ixj > tid) {
                unsigned a = key[tid], b = key[ixj];
                bool asc = (tid & k) == 0;
                if (asc ? (a > b) : (a < b)) { key[tid] = b; key[ixj] = a; }
            }
        }
    }
    __syncthreads();
    if (t < n_nodes)
        perm[t] = base + (int)(key[tid] & 0xFFFFu);   // real nodes occupy front
}

// ---------------------------------------------------------------------------
// Kernel 2 (MFMA GEMM): H = x_bf16 @ WcT^T. Same math/tiling as before; NEW:
// epilogue bounces C through the (now free) Xs LDS tile and stores coalesced
// uint4 (8 bf16) instead of 64 scalar 2-byte global stores per thread.
// ---------------------------------------------------------------------------
__global__ __launch_bounds__(256, 3)
void gemm_kernel(const float* __restrict__ x,
                 const unsigned short* __restrict__ WcT,
                 unsigned short* __restrict__ Abf,
                 unsigned short* __restrict__ Bbf,
                 int n_nodes)
{
    __shared__ unsigned short Xs[M_TILE][XS_PITCH];   // 34.8 KB

    const int tid  = threadIdx.x;
    const int w    = tid >> 6;
    const int lane = tid & 63;
    const int l15  = lane & 15;
    const int quad = lane >> 4;
    const long long node0 = (long long)blockIdx.x * M_TILE;

    short8 bfrag[4][2];
#pragma unroll
    for (int ks = 0; ks < 4; ++ks)
#pragma unroll
        for (int ni = 0; ni < 2; ++ni)
            bfrag[ks][ni] = *(const short8*)&WcT[(w * 32 + ni * 16 + l15) * IN_CH
                                                 + ks * 32 + quad * 8];

    {
        const float4* x4 = (const float4*)x;
        for (int i = tid; i < M_TILE * (IN_CH / 4); i += 256) {
            int row = i >> 5, c4 = i & 31;
            long long node = node0 + row;
            float4 v = make_float4(0.f, 0.f, 0.f, 0.f);
            if (node < n_nodes) v = x4[node * (IN_CH / 4) + c4];
            uint2 p;
            p.x = ((unsigned)f2bf(v.y) << 16) | f2bf(v.x);
            p.y = ((unsigned)f2bf(v.w) << 16) | f2bf(v.z);
            *(uint2*)&Xs[row][c4 * 4] = p;
        }
    }
    __syncthreads();

    floatx4 acc[8][2];
#pragma unroll
    for (int mi = 0; mi < 8; ++mi)
#pragma unroll
        for (int ni = 0; ni < 2; ++ni)
            acc[mi][ni] = (floatx4){0.f, 0.f, 0.f, 0.f};

#pragma unroll
    for (int ks = 0; ks < 4; ++ks) {
        const int k0 = ks * 32 + quad * 8;
#pragma unroll
        for (int mi = 0; mi < 8; ++mi) {
            short8 a = *(const short8*)&Xs[mi * 16 + l15][k0];
            acc[mi][0] = __builtin_amdgcn_mfma_f32_16x16x32_bf16(a, bfrag[ks][0], acc[mi][0], 0, 0, 0);
            acc[mi][1] = __builtin_amdgcn_mfma_f32_16x16x32_bf16(a, bfrag[ks][1], acc[mi][1], 0, 0, 0);
        }
    }

    // ---- epilogue: acc -> LDS (bf16, full 128x128 tile), then coalesced out
    __syncthreads();                       // Xs reads done; safe to overwrite
    const int colb = w * 32;               // global col = w*32 + ni*16 + l15
#pragma unroll
    for (int mi = 0; mi < 8; ++mi)
#pragma unroll
        for (int ni = 0; ni < 2; ++ni)
#pragma unroll
            for (int r = 0; r < 4; ++r)
                Xs[mi * 16 + quad * 4 + r][colb + ni * 16 + l15] =
                    f2bf(acc[mi][ni][r]);
    __syncthreads();

    // rows 0..127; cols 0..63 -> Abf row, cols 64..127 -> Bbf row.
    // 128 rows x 2 halves x 8 uint4 = 2048 stores / 256 thr = 8 per thread.
    for (int i = tid; i < M_TILE * 16; i += 256) {
        int row  = i >> 4;
        int half = (i >> 3) & 1;
        int v4   = i & 7;
        long long node = node0 + row;
        if (node < n_nodes) {
            uint4 v = *(const uint4*)&Xs[row][half * 64 + v4 * 8];
            unsigned short* dst = half ? Bbf : Abf;
            *(uint4*)&dst[node * OUT_CH + v4 * 8] = v;
        }
    }
}

// ---------------------------------------------------------------------------
// Kernel 3: segmented weighted gather-sum + epilogue.
// R1's proven pipelined eighth-wave structure with perm[] from the WINDOWED
// sort: groups of 8 have near-equal degree (padding ~+5%) AND stay inside a
// 256-node window (edge-stream locality preserved).
// ---------------------------------------------------------------------------
__global__ __launch_bounds__(256)
void prop_kernel(const unsigned short* __restrict__ H,   // A base; B = A + Boff
                 const int* __restrict__ rpIn, const int* __restrict__ rpOut,
                 const int* __restrict__ srcIn, const float* __restrict__ ewIn,
                 const int* __restrict__ srcOut, const float* __restrict__ ewOut,
                 const int* __restrict__ perm,
                 const float* __restrict__ bmi, const float* __restrict__ bmo,
                 const float* __restrict__ bsi, const float* __restrict__ bso,
                 const float* __restrict__ Cin, const float* __restrict__ Cout,
                 float* __restrict__ out, int n_nodes, int neIn, int neOut)
{
    const int lane = threadIdx.x & 63;
    const int wv   = threadIdx.x >> 6;
    const int e    = lane >> 3;           // eighth: which node of the eight
    const int el   = lane & 7;            // lane within eighth
    const int ch8  = el * 8;              // first of my 8 channels
    const int eb   = lane & 56;           // eighth base lane

    const unsigned short* Hq = H + ch8;   // per-lane channel-offset base

    const int t = ((int)blockIdx.x * 4 + wv) * 8 + e;
    const bool valid = (t < n_nodes);
    const int tc = valid ? perm[t] : 0;   // window-degree-sorted node id

    const int Boff = n_nodes * OUT_CH;    // element offset of B within H

    int ei0 = rpIn[tc],  ei1 = rpIn[tc + 1];
    int eo0 = rpOut[tc], eo1 = rpOut[tc + 1];
    int dIn  = ei1 - ei0;
    int len  = valid ? (dIn + (eo1 - eo0)) : 0;
    float ci = Cin[tc], co = Cout[tc];

    // Wave-uniform max combined length across the eight eighths (butterfly)
    int ml = len;
    ml = max(ml, __shfl_xor(ml, 8));
    ml = max(ml, __shfl_xor(ml, 16));
    ml = max(ml, __shfl_xor(ml, 32));
    const int maxlen = __builtin_amdgcn_readfirstlane(ml);

    float a0 = 0.f, a1 = 0.f, a2 = 0.f, a3 = 0.f;
    float a4 = 0.f, a5 = 0.f, a6 = 0.f, a7 = 0.f;

    // ---- raw pack loader: slot j of MY eighth's concatenated stream
    auto load_raw = [&](int j, int& sI, float& wI, int& sO, float& wO) {
        int iIn  = min(ei0 + max(0, min(j, dIn - 1)), neIn - 1);
        int jo   = j - dIn;
        int iOut = min(eo0 + max(0, jo), neOut - 1);
        sI = srcIn[iIn];  wI = ewIn[iIn];
        sO = srcOut[iOut]; wO = ewOut[iOut];
    };

    // ---- convert raw (sI,wI,sO,wO) at slot base p into (rowb, wj)
    auto conv = [&](int p, int sI, float wI, int sO, float wO,
                    int& rowb, float& wj) {
        int j = p + el;
        bool inSeg  = (j < dIn);
        bool anySeg = (j < len);
        int rb = inSeg ? (sI * OUT_CH) : (sO * OUT_CH + Boff);
        rowb = anySeg ? rb : 0;
        wj   = inSeg ? (ci * wI) : (anySeg ? (co * wO) : 0.f);
    };

    // ---- issue the 8 uint4 gathers of one pack (rows broadcast within eighth)
    auto gather = [&](int rowb, uint4 (&u)[8]) {
        int r0 = __shfl(rowb, eb + 0), r1 = __shfl(rowb, eb + 1);
        int r2 = __shfl(rowb, eb + 2), r3 = __shfl(rowb, eb + 3);
        int r4 = __shfl(rowb, eb + 4), r5 = __shfl(rowb, eb + 5);
        int r6 = __shfl(rowb, eb + 6), r7 = __shfl(rowb, eb + 7);
        u[0] = *(const uint4*)(Hq + r0);
        u[1] = *(const uint4*)(Hq + r1);
        u[2] = *(const uint4*)(Hq + r2);
        u[3] = *(const uint4*)(Hq + r3);
        u[4] = *(const uint4*)(Hq + r4);
        u[5] = *(const uint4*)(Hq + r5);
        u[6] = *(const uint4*)(Hq + r6);
        u[7] = *(const uint4*)(Hq + r7);
    };

    // ---- consume one pack: broadcast weights at use time, 128 FMAs
    auto consume = [&](const uint4 (&u)[8], float wj) {
#pragma unroll
        for (int k = 0; k < 8; ++k) {
            float wk = __shfl(wj, eb + k);
            uint4 uk = u[k];
            a0 += wk * bfl(uk.x); a1 += wk * bfh(uk.x);
            a2 += wk * bfl(uk.y); a3 += wk * bfh(uk.y);
            a4 += wk * bfl(uk.z); a5 += wk * bfh(uk.z);
            a6 += wk * bfl(uk.w); a7 += wk * bfh(uk.w);
        }
    };

    int   sIa, sOa, sIb, sOb;
    float wIa, wOa, wIb, wOb;
    uint4 uA[8], uB[8];
    float wjA = 0.f, wjB = 0.f;

    // ---- prologue: fill both pipeline stages
    load_raw(el,     sIa, wIa, sOa, wOa);    // pack offset 0 raws
    load_raw(8 + el, sIb, wIb, sOb, wOb);    // pack offset 8 raws
    {
        int rb; conv(0, sIa, wIa, sOa, wOa, rb, wjA);
        gather(rb, uA);                       // pack 0 gathers in flight
    }
    load_raw(16 + el, sIa, wIa, sOa, wOa);   // pack 16 raws (in flight)
    {
        int rb; conv(8, sIb, wIb, sOb, wOb, rb, wjB);
        gather(rb, uB);                       // pack 8 gathers in flight
    }
    load_raw(24 + el, sIb, wIb, sOb, wOb);   // pack 24 raws (in flight)

    // ---- steady state: consume pack p / p+8, prep pack p+16 / p+24
    for (int p = 0; p < maxlen; p += 16) {
        consume(uA, wjA);                     // pack p
        if (p + 16 < maxlen) {
            int rb; conv(p + 16, sIa, wIa, sOa, wOa, rb, wjA);
            load_raw(p + 32 + el, sIa, wIa, sOa, wOa);
            gather(rb, uA);                   // pack p+16 in flight
        }
        if (p + 8 < maxlen) consume(uB, wjB); // pack p+8
        if (p + 24 < maxlen) {
            int rb; conv(p + 24, sIb, wIb, sOb, wOb, rb, wjB);
            load_raw(p + 40 + el, sIb, wIb, sOb, wOb);
            gather(rb, uB);                   // pack p+24 in flight
        }
    }

    if (valid) {
        float4 o0, o1;
        o0.x = a0 + ci * (bmi[ch8 + 0] + bsi[ch8 + 0]) + co * (bmo[ch8 + 0] + bso[ch8 + 0]);
        o0.y = a1 + ci * (bmi[ch8 + 1] + bsi[ch8 + 1]) + co * (bmo[ch8 + 1] + bso[ch8 + 1]);
        o0.z = a2 + ci * (bmi[ch8 + 2] + bsi[ch8 + 2]) + co * (bmo[ch8 + 2] + bso[ch8 + 2]);
        o0.w = a3 + ci * (bmi[ch8 + 3] + bsi[ch8 + 3]) + co * (bmo[ch8 + 3] + bso[ch8 + 3]);
        o1.x = a4 + ci * (bmi[ch8 + 4] + bsi[ch8 + 4]) + co * (bmo[ch8 + 4] + bso[ch8 + 4]);
        o1.y = a5 + ci * (bmi[ch8 + 5] + bsi[ch8 + 5]) + co * (bmo[ch8 + 5] + bso[ch8 + 5]);
        o1.z = a6 + ci * (bmi[ch8 + 6] + bsi[ch8 + 6]) + co * (bmo[ch8 + 6] + bso[ch8 + 6]);
        o1.w = a7 + ci * (bmi[ch8 + 7] + bsi[ch8 + 7]) + co * (bmo[ch8 + 7] + bso[ch8 + 7]);
        float* ob = out + (long long)tc * OUT_CH + ch8;
        *(float4*)ob = o0;
        *(float4*)(ob + 4) = o1;
    }
}

// ---------------------------------------------------------------------------
extern "C" void kernel_launch(void* const* d_in, const int* in_sizes, int n_in,
                              void* d_out, int out_size, void* d_ws, size_t ws_size,
                              hipStream_t stream)
{
    const float* x    = (const float*)d_in[0];
    const float* Wmi  = (const float*)d_in[1];
    const float* Wmo  = (const float*)d_in[2];
    const float* Wsh  = (const float*)d_in[3];
    const float* bmi  = (const float*)d_in[4];
    const float* bmo  = (const float*)d_in[5];
    const float* bsi  = (const float*)d_in[6];
    const float* bso  = (const float*)d_in[7];
    const float* Cin  = (const float*)d_in[8];
    const float* Cout = (const float*)d_in[9];
    const int*   eiIn  = (const int*)d_in[10];
    const float* ewIn  = (const float*)d_in[11];
    const int*   eiOut = (const int*)d_in[12];
    const float* ewOut = (const float*)d_in[13];

    const int n_nodes = in_sizes[0] / IN_CH;   // 100000
    const int neIn  = in_sizes[11];            // 1000000
    const int neOut = in_sizes[13];

    const int* srcIn  = eiIn;                  // edge_index[0]
    const int* tgtIn  = eiIn + neIn;           // edge_index[1] (sorted)
    const int* srcOut = eiOut;
    const int* tgtOut = eiOut + neOut;

    // Workspace: Abf|Bbf (bf16) | rpIn | rpOut | WcT (bf16) | perm
    char* ws = (char*)d_ws;
    size_t NH = (size_t)n_nodes * OUT_CH * sizeof(unsigned short);
    unsigned short* Abf = (unsigned short*)ws;
    unsigned short* Bbf = (unsigned short*)(ws + NH);
    int* rpIn  = (int*)(ws + 2 * NH);
    int* rpOut = rpIn + (n_nodes + 1);
    unsigned short* WcT = (unsigned short*)(rpOut + (n_nodes + 1));
    int* perm = (int*)(WcT + 2 * OUT_CH * IN_CH);

    // 1) rowptrs + combined-weight bf16 pre-pack
    int prep_threads = 2 * (n_nodes + 1) + 2 * OUT_CH * IN_CH;
    prep_kernel<<<(prep_threads + 255) / 256, 256, 0, stream>>>(
        tgtIn, tgtOut, Wmi, Wmo, Wsh, rpIn, rpOut, WcT, n_nodes, neIn, neOut);

    // 1b) window-local degree sort -> perm (one kernel, LDS bitonic)
    int wblocks = (n_nodes + 255) / 256;
    wsort_kernel<<<wblocks, 256, 0, stream>>>(rpIn, rpOut, perm, n_nodes);

    // 2) fused dense transform via MFMA (N=128 GEMM: [A|B] columns)
    int gblocks = (n_nodes + M_TILE - 1) / M_TILE;
    gemm_kernel<<<gblocks, 256, 0, stream>>>(x, WcT, Abf, Bbf, n_nodes);

    // 3) segmented gather-sum + epilogue (pipelined, window-sorted groups)
    int pblocks = (n_nodes + 31) / 32;         // 32 nodes per block
    prop_kernel<<<pblocks, 256, 0, stream>>>(
        Abf, rpIn, rpOut, srcIn, ewIn, srcOut, ewOut, perm,
        bmi, bmo, bsi, bso, Cin, Cout, (float*)d_out, n_nodes, neIn, neOut);
}

// Round 6
// 182.299 us; speedup vs baseline: 4.1423x; 1.1280x over previous
//
#include <hip/hip_runtime.h>

#define IN_CH   128
#define OUT_CH  64
#define M_TILE  128         // nodes per block in the MFMA GEMM
#define XS_PITCH 136        // 128 bf16 + 8 pad (272 B row) -> conflict-free frags

typedef __attribute__((ext_vector_type(8))) short short8;
typedef __attribute__((ext_vector_type(4))) float floatx4;

__device__ __forceinline__ unsigned short f2bf(float f) {
    union { float f; unsigned u; } v; v.f = f;
    unsigned r = v.u + 0x7fffu + ((v.u >> 16) & 1u);   // RNE
    return (unsigned short)(r >> 16);
}
__device__ __forceinline__ float bfl(unsigned u) {   // low bf16 -> f32
    return __uint_as_float(u << 16);
}
__device__ __forceinline__ float bfh(unsigned u) {   // high bf16 -> f32
    return __uint_as_float(u & 0xffff0000u);
}

// ---------------------------------------------------------------------------
// Kernel 1 (prep): CSR row pointers + bf16 pre-pack of combined weights.
// R6 CHANGE: rowptrs via EDGE-PARALLEL difference scan instead of per-node
// binary search. Old: 200K threads x ~20 DEPENDENT scattered loads (pure
// latency chains). New: thread i reads tgt[i-1], tgt[i] (coalesced stream)
// and writes rp[t]=i for all t in (tgt[i-1], tgt[i]] (avg 0.1 writes/thread).
// Tail thread (i==ne) fills (tgt[ne-1], n_nodes]. No dependent chains.
// ---------------------------------------------------------------------------
__global__ void prep_kernel(const int* __restrict__ tgtIn,
                            const int* __restrict__ tgtOut,
                            const float* __restrict__ Wmi,
                            const float* __restrict__ Wmo,
                            const float* __restrict__ Wsh,
                            int* __restrict__ rpIn,
                            int* __restrict__ rpOut,
                            unsigned short* __restrict__ WcT,
                            int n_nodes, int neIn, int neOut)
{
    int i = blockIdx.x * blockDim.x + threadIdx.x;
    const int nIn1 = neIn + 1, nOut1 = neOut + 1;

    if (i < nIn1 + nOut1) {
        const int* tgt; int* rp; int idx; int ne;
        if (i < nIn1) { tgt = tgtIn;  rp = rpIn;  idx = i;        ne = neIn; }
        else          { tgt = tgtOut; rp = rpOut; idx = i - nIn1; ne = neOut; }
        if (idx < ne) {
            int a    = tgt[idx];
            int prev = (idx == 0) ? -1 : tgt[idx - 1];
            for (int t = prev + 1; t <= a; ++t) rp[t] = idx;
        } else {
            int last = (ne > 0) ? tgt[ne - 1] : -1;
            for (int t = last + 1; t <= n_nodes; ++t) rp[t] = ne;
        }
    } else {
        int j = i - (nIn1 + nOut1);
        if (j < 2 * OUT_CH * IN_CH) {
            int n = j >> 7, k = j & 127;     // n: output col of Wc, k: input ch
            float m = (n < OUT_CH) ? Wmi[k * OUT_CH + n]
                                   : Wmo[k * OUT_CH + (n - OUT_CH)];
            float s = Wsh[k * OUT_CH + (n & (OUT_CH - 1))];
            WcT[n * IN_CH + k] = f2bf(m + s);
        }
    }
}

// ---------------------------------------------------------------------------
// Kernel 2 (MFMA GEMM): H = x_bf16 @ WcT^T. Main loop proven; epilogue
// bounces C through the (free) Xs LDS tile -> coalesced uint4 stores
// (kept from R5; this round isolates its effect vs R1's scalar stores).
// ---------------------------------------------------------------------------
__global__ __launch_bounds__(256, 3)
void gemm_kernel(const float* __restrict__ x,
                 const unsigned short* __restrict__ WcT,
                 unsigned short* __restrict__ Abf,
                 unsigned short* __restrict__ Bbf,
                 int n_nodes)
{
    __shared__ unsigned short Xs[M_TILE][XS_PITCH];   // 34.8 KB

    const int tid  = threadIdx.x;
    const int w    = tid >> 6;
    const int lane = tid & 63;
    const int l15  = lane & 15;
    const int quad = lane >> 4;
    const long long node0 = (long long)blockIdx.x * M_TILE;

    short8 bfrag[4][2];
#pragma unroll
    for (int ks = 0; ks < 4; ++ks)
#pragma unroll
        for (int ni = 0; ni < 2; ++ni)
            bfrag[ks][ni] = *(const short8*)&WcT[(w * 32 + ni * 16 + l15) * IN_CH
                                                 + ks * 32 + quad * 8];

    {
        const float4* x4 = (const float4*)x;
        for (int i = tid; i < M_TILE * (IN_CH / 4); i += 256) {
            int row = i >> 5, c4 = i & 31;
            long long node = node0 + row;
            float4 v = make_float4(0.f, 0.f, 0.f, 0.f);
            if (node < n_nodes) v = x4[node * (IN_CH / 4) + c4];
            uint2 p;
            p.x = ((unsigned)f2bf(v.y) << 16) | f2bf(v.x);
            p.y = ((unsigned)f2bf(v.w) << 16) | f2bf(v.z);
            *(uint2*)&Xs[row][c4 * 4] = p;
        }
    }
    __syncthreads();

    floatx4 acc[8][2];
#pragma unroll
    for (int mi = 0; mi < 8; ++mi)
#pragma unroll
        for (int ni = 0; ni < 2; ++ni)
            acc[mi][ni] = (floatx4){0.f, 0.f, 0.f, 0.f};

#pragma unroll
    for (int ks = 0; ks < 4; ++ks) {
        const int k0 = ks * 32 + quad * 8;
#pragma unroll
        for (int mi = 0; mi < 8; ++mi) {
            short8 a = *(const short8*)&Xs[mi * 16 + l15][k0];
            acc[mi][0] = __builtin_amdgcn_mfma_f32_16x16x32_bf16(a, bfrag[ks][0], acc[mi][0], 0, 0, 0);
            acc[mi][1] = __builtin_amdgcn_mfma_f32_16x16x32_bf16(a, bfrag[ks][1], acc[mi][1], 0, 0, 0);
        }
    }

    // ---- epilogue: acc -> LDS (bf16, full 128x128 tile), then coalesced out
    __syncthreads();                       // Xs reads done; safe to overwrite
    const int colb = w * 32;               // global col = w*32 + ni*16 + l15
#pragma unroll
    for (int mi = 0; mi < 8; ++mi)
#pragma unroll
        for (int ni = 0; ni < 2; ++ni)
#pragma unroll
            for (int r = 0; r < 4; ++r)
                Xs[mi * 16 + quad * 4 + r][colb + ni * 16 + l15] =
                    f2bf(acc[mi][ni][r]);
    __syncthreads();

    // rows 0..127; cols 0..63 -> Abf row, cols 64..127 -> Bbf row.
    // 128 rows x 2 halves x 8 uint4 = 2048 stores / 256 thr = 8 per thread.
    for (int i = tid; i < M_TILE * 16; i += 256) {
        int row  = i >> 4;
        int half = (i >> 3) & 1;
        int v4   = i & 7;
        long long node = node0 + row;
        if (node < n_nodes) {
            uint4 v = *(const uint4*)&Xs[row][half * 64 + v4 * 8];
            unsigned short* dst = half ? Bbf : Abf;
            *(uint4*)&dst[node * OUT_CH + v4 * 8] = v;
        }
    }
}

// ---------------------------------------------------------------------------
// Kernel 3: segmented weighted gather-sum + epilogue.
// R1's proven pipelined eighth-wave structure, VERBATIM, no permutation.
// (R4 global sort and R5 window sort both measured WORSE: reordering
// targets scatters edge-stream/rp/out accesses, +30-40 MB FETCH, +14 us.
// Padding waste is cheaper than lost locality. Natural order is final.)
// ---------------------------------------------------------------------------
__global__ __launch_bounds__(256)
void prop_kernel(const unsigned short* __restrict__ H,   // A base; B = A + Boff
                 const int* __restrict__ rpIn, const int* __restrict__ rpOut,
                 const int* __restrict__ srcIn, const float* __restrict__ ewIn,
                 const int* __restrict__ srcOut, const float* __restrict__ ewOut,
                 const float* __restrict__ bmi, const float* __restrict__ bmo,
                 const float* __restrict__ bsi, const float* __restrict__ bso,
                 const float* __restrict__ Cin, const float* __restrict__ Cout,
                 float* __restrict__ out, int n_nodes, int neIn, int neOut)
{
    const int lane = threadIdx.x & 63;
    const int wv   = threadIdx.x >> 6;
    const int e    = lane >> 3;           // eighth: which node of the eight
    const int el   = lane & 7;            // lane within eighth
    const int ch8  = el * 8;              // first of my 8 channels
    const int eb   = lane & 56;           // eighth base lane

    const unsigned short* Hq = H + ch8;   // per-lane channel-offset base

    const int t = ((int)blockIdx.x * 4 + wv) * 8 + e;
    const bool valid = (t < n_nodes);
    const int tc = valid ? t : 0;

    const int Boff = n_nodes * OUT_CH;    // element offset of B within H

    int ei0 = rpIn[tc],  ei1 = rpIn[tc + 1];
    int eo0 = rpOut[tc], eo1 = rpOut[tc + 1];
    int dIn  = ei1 - ei0;
    int len  = valid ? (dIn + (eo1 - eo0)) : 0;
    float ci = Cin[tc], co = Cout[tc];

    // Wave-uniform max combined length across the eight eighths (butterfly)
    int ml = len;
    ml = max(ml, __shfl_xor(ml, 8));
    ml = max(ml, __shfl_xor(ml, 16));
    ml = max(ml, __shfl_xor(ml, 32));
    const int maxlen = __builtin_amdgcn_readfirstlane(ml);

    float a0 = 0.f, a1 = 0.f, a2 = 0.f, a3 = 0.f;
    float a4 = 0.f, a5 = 0.f, a6 = 0.f, a7 = 0.f;

    // ---- raw pack loader: slot j of MY eighth's concatenated stream
    auto load_raw = [&](int j, int& sI, float& wI, int& sO, float& wO) {
        int iIn  = min(ei0 + max(0, min(j, dIn - 1)), neIn - 1);
        int jo   = j - dIn;
        int iOut = min(eo0 + max(0, jo), neOut - 1);
        sI = srcIn[iIn];  wI = ewIn[iIn];
        sO = srcOut[iOut]; wO = ewOut[iOut];
    };

    // ---- convert raw (sI,wI,sO,wO) at slot base p into (rowb, wj)
    auto conv = [&](int p, int sI, float wI, int sO, float wO,
                    int& rowb, float& wj) {
        int j = p + el;
        bool inSeg  = (j < dIn);
        bool anySeg = (j < len);
        int rb = inSeg ? (sI * OUT_CH) : (sO * OUT_CH + Boff);
        rowb = anySeg ? rb : 0;
        wj   = inSeg ? (ci * wI) : (anySeg ? (co * wO) : 0.f);
    };

    // ---- issue the 8 uint4 gathers of one pack (rows broadcast within eighth)
    auto gather = [&](int rowb, uint4 (&u)[8]) {
        int r0 = __shfl(rowb, eb + 0), r1 = __shfl(rowb, eb + 1);
        int r2 = __shfl(rowb, eb + 2), r3 = __shfl(rowb, eb + 3);
        int r4 = __shfl(rowb, eb + 4), r5 = __shfl(rowb, eb + 5);
        int r6 = __shfl(rowb, eb + 6), r7 = __shfl(rowb, eb + 7);
        u[0] = *(const uint4*)(Hq + r0);
        u[1] = *(const uint4*)(Hq + r1);
        u[2] = *(const uint4*)(Hq + r2);
        u[3] = *(const uint4*)(Hq + r3);
        u[4] = *(const uint4*)(Hq + r4);
        u[5] = *(const uint4*)(Hq + r5);
        u[6] = *(const uint4*)(Hq + r6);
        u[7] = *(const uint4*)(Hq + r7);
    };

    // ---- consume one pack: broadcast weights at use time, 128 FMAs
    auto consume = [&](const uint4 (&u)[8], float wj) {
#pragma unroll
        for (int k = 0; k < 8; ++k) {
            float wk = __shfl(wj, eb + k);
            uint4 uk = u[k];
            a0 += wk * bfl(uk.x); a1 += wk * bfh(uk.x);
            a2 += wk * bfl(uk.y); a3 += wk * bfh(uk.y);
            a4 += wk * bfl(uk.z); a5 += wk * bfh(uk.z);
            a6 += wk * bfl(uk.w); a7 += wk * bfh(uk.w);
        }
    };

    int   sIa, sOa, sIb, sOb;
    float wIa, wOa, wIb, wOb;
    uint4 uA[8], uB[8];
    float wjA = 0.f, wjB = 0.f;

    // ---- prologue: fill both pipeline stages
    load_raw(el,     sIa, wIa, sOa, wOa);    // pack offset 0 raws
    load_raw(8 + el, sIb, wIb, sOb, wOb);    // pack offset 8 raws
    {
        int rb; conv(0, sIa, wIa, sOa, wOa, rb, wjA);
        gather(rb, uA);                       // pack 0 gathers in flight
    }
    load_raw(16 + el, sIa, wIa, sOa, wOa);   // pack 16 raws (in flight)
    {
        int rb; conv(8, sIb, wIb, sOb, wOb, rb, wjB);
        gather(rb, uB);                       // pack 8 gathers in flight
    }
    load_raw(24 + el, sIb, wIb, sOb, wOb);   // pack 24 raws (in flight)

    // ---- steady state: consume pack p / p+8, prep pack p+16 / p+24
    for (int p = 0; p < maxlen; p += 16) {
        consume(uA, wjA);                     // pack p
        if (p + 16 < maxlen) {
            int rb; conv(p + 16, sIa, wIa, sOa, wOa, rb, wjA);
            load_raw(p + 32 + el, sIa, wIa, sOa, wOa);
            gather(rb, uA);                   // pack p+16 in flight
        }
        if (p + 8 < maxlen) consume(uB, wjB); // pack p+8
        if (p + 24 < maxlen) {
            int rb; conv(p + 24, sIb, wIb, sOb, wOb, rb, wjB);
            load_raw(p + 40 + el, sIb, wIb, sOb, wOb);
            gather(rb, uB);                   // pack p+24 in flight
        }
    }

    if (valid) {
        float4 o0, o1;
        o0.x = a0 + ci * (bmi[ch8 + 0] + bsi[ch8 + 0]) + co * (bmo[ch8 + 0] + bso[ch8 + 0]);
        o0.y = a1 + ci * (bmi[ch8 + 1] + bsi[ch8 + 1]) + co * (bmo[ch8 + 1] + bso[ch8 + 1]);
        o0.z = a2 + ci * (bmi[ch8 + 2] + bsi[ch8 + 2]) + co * (bmo[ch8 + 2] + bso[ch8 + 2]);
        o0.w = a3 + ci * (bmi[ch8 + 3] + bsi[ch8 + 3]) + co * (bmo[ch8 + 3] + bso[ch8 + 3]);
        o1.x = a4 + ci * (bmi[ch8 + 4] + bsi[ch8 + 4]) + co * (bmo[ch8 + 4] + bso[ch8 + 4]);
        o1.y = a5 + ci * (bmi[ch8 + 5] + bsi[ch8 + 5]) + co * (bmo[ch8 + 5] + bso[ch8 + 5]);
        o1.z = a6 + ci * (bmi[ch8 + 6] + bsi[ch8 + 6]) + co * (bmo[ch8 + 6] + bso[ch8 + 6]);
        o1.w = a7 + ci * (bmi[ch8 + 7] + bsi[ch8 + 7]) + co * (bmo[ch8 + 7] + bso[ch8 + 7]);
        float* ob = out + (long long)t * OUT_CH + ch8;
        *(float4*)ob = o0;
        *(float4*)(ob + 4) = o1;
    }
}

// ---------------------------------------------------------------------------
extern "C" void kernel_launch(void* const* d_in, const int* in_sizes, int n_in,
                              void* d_out, int out_size, void* d_ws, size_t ws_size,
                              hipStream_t stream)
{
    const float* x    = (const float*)d_in[0];
    const float* Wmi  = (const float*)d_in[1];
    const float* Wmo  = (const float*)d_in[2];
    const float* Wsh  = (const float*)d_in[3];
    const float* bmi  = (const float*)d_in[4];
    const float* bmo  = (const float*)d_in[5];
    const float* bsi  = (const float*)d_in[6];
    const float* bso  = (const float*)d_in[7];
    const float* Cin  = (const float*)d_in[8];
    const float* Cout = (const float*)d_in[9];
    const int*   eiIn  = (const int*)d_in[10];
    const float* ewIn  = (const float*)d_in[11];
    const int*   eiOut = (const int*)d_in[12];
    const float* ewOut = (const float*)d_in[13];

    const int n_nodes = in_sizes[0] / IN_CH;   // 100000
    const int neIn  = in_sizes[11];            // 1000000
    const int neOut = in_sizes[13];

    const int* srcIn  = eiIn;                  // edge_index[0]
    const int* tgtIn  = eiIn + neIn;           // edge_index[1] (sorted)
    const int* srcOut = eiOut;
    const int* tgtOut = eiOut + neOut;

    // Workspace layout: Abf|Bbf contiguous (bf16) | rpIn | rpOut | WcT (bf16)
    char* ws = (char*)d_ws;
    size_t NH = (size_t)n_nodes * OUT_CH * sizeof(unsigned short);
    unsigned short* Abf = (unsigned short*)ws;
    unsigned short* Bbf = (unsigned short*)(ws + NH);
    int* rpIn  = (int*)(ws + 2 * NH);
    int* rpOut = rpIn + (n_nodes + 1);
    unsigned short* WcT = (unsigned short*)(rpOut + (n_nodes + 1));

    // 1) rowptrs (edge-parallel diff scan) + combined-weight bf16 pre-pack
    int prep_threads = (neIn + 1) + (neOut + 1) + 2 * OUT_CH * IN_CH;
    prep_kernel<<<(prep_threads + 255) / 256, 256, 0, stream>>>(
        tgtIn, tgtOut, Wmi, Wmo, Wsh, rpIn, rpOut, WcT, n_nodes, neIn, neOut);

    // 2) fused dense transform via MFMA (N=128 GEMM: [A|B] columns)
    int gblocks = (n_nodes + M_TILE - 1) / M_TILE;
    gemm_kernel<<<gblocks, 256, 0, stream>>>(x, WcT, Abf, Bbf, n_nodes);

    // 3) segmented gather-sum + epilogue (pipelined eighth-wave per node)
    int pblocks = (n_nodes + 31) / 32;         // 32 nodes per block
    prop_kernel<<<pblocks, 256, 0, stream>>>(
        Abf, rpIn, rpOut, srcIn, ewIn, srcOut, ewOut,
        bmi, bmo, bsi, bso, Cin, Cout, (float*)d_out, n_nodes, neIn, neOut);
}